// Round 4
// baseline (571.432 us; speedup 1.0000x reference)
//
#include <hip/hip_runtime.h>

#define CH 64
#define BN_EPS 1e-5f

typedef __attribute__((ext_vector_type(8))) __bf16 bf16x8;
typedef __attribute__((ext_vector_type(4))) float f32x4;

__device__ __forceinline__ float silu_f(float x) { return x / (1.0f + __expf(-x)); }

// ---------------------------------------------------------------------------
// Kernel: h = x @ Win + bin ; accumulate per-channel sum/sumsq for BN1
// ---------------------------------------------------------------------------
__global__ __launch_bounds__(256) void k_lin_in(
    const float* __restrict__ x, const float* __restrict__ Win, const float* __restrict__ bin,
    float* __restrict__ h, float* __restrict__ ssum, float* __restrict__ ssq, int N)
{
    __shared__ float xt[64 * 64];
    __shared__ float Wl[64 * 64];
    __shared__ float red[2][4][64];
    const int t = threadIdx.x, c = t & 63, g = t >> 6;
    const int row0 = blockIdx.x * 64;

    for (int i = t; i < 64 * 64; i += 256) {
        int r = i >> 6, cc = i & 63;
        int gr = row0 + r;
        xt[i] = (gr < N) ? x[(size_t)gr * CH + cc] : 0.0f;
        Wl[i] = Win[i];
    }
    __syncthreads();

    float acc[16];
    const float b = bin[c];
#pragma unroll
    for (int i = 0; i < 16; ++i) acc[i] = b;
    for (int k = 0; k < 64; ++k) {
        float w = Wl[k * 64 + c];
#pragma unroll
        for (int i = 0; i < 16; ++i) acc[i] += xt[(g * 16 + i) * 64 + k] * w;
    }
    float s = 0.0f, ss = 0.0f;
#pragma unroll
    for (int i = 0; i < 16; ++i) {
        int gr = row0 + g * 16 + i;
        if (gr < N) {
            h[(size_t)gr * CH + c] = acc[i];
            s += acc[i];
            ss += acc[i] * acc[i];
        }
    }
    red[0][g][c] = s;
    red[1][g][c] = ss;
    __syncthreads();
    if (g == 0) {
        atomicAdd(&ssum[c], red[0][0][c] + red[0][1][c] + red[0][2][c] + red[0][3][c]);
        atomicAdd(&ssq[c],  red[1][0][c] + red[1][1][c] + red[1][2][c] + red[1][3][c]);
    }
}

// ---------------------------------------------------------------------------
__global__ void k_stats(const float* __restrict__ ssum, const float* __restrict__ ssq,
                        const float* __restrict__ gamma, const float* __restrict__ beta,
                        float* __restrict__ scale, float* __restrict__ shift, int N)
{
    int c = threadIdx.x;
    float inv = 1.0f / (float)N;
    float mu = ssum[c] * inv;
    float var = ssq[c] * inv - mu * mu;
    float sc = gamma[c] * rsqrtf(var + BN_EPS);
    scale[c] = sc;
    shift[c] = beta[c] - mu * sc;
}

// ---------------------------------------------------------------------------
// Kernel: x1 = silu(h*scale+shift); v/k/q = x1@W — stored as bf16
// ---------------------------------------------------------------------------
__global__ __launch_bounds__(256) void k_vkq(
    const float* __restrict__ h, const float* __restrict__ scale, const float* __restrict__ shift,
    const float* __restrict__ Wv, const float* __restrict__ Wk, const float* __restrict__ Wq,
    __bf16* __restrict__ vv, __bf16* __restrict__ kk, __bf16* __restrict__ qq, int N)
{
    __shared__ float xt[64 * 64];
    __shared__ float Wl[2][64 * 64];
    const int t = threadIdx.x, c = t & 63, g = t >> 6;
    const int row0 = blockIdx.x * 64;

    for (int i = t; i < 64 * 64; i += 256) {
        int r = i >> 6, cc = i & 63;
        int gr = row0 + r;
        float hv = (gr < N) ? h[(size_t)gr * CH + cc] : 0.0f;
        xt[i] = silu_f(hv * scale[cc] + shift[cc]);
        Wl[0][i] = Wv[i];
        Wl[1][i] = Wk[i];
    }
    __syncthreads();

    for (int m = 0; m < 2; ++m) {
        float acc[16];
#pragma unroll
        for (int i = 0; i < 16; ++i) acc[i] = 0.0f;
        for (int k = 0; k < 64; ++k) {
            float w = Wl[m][k * 64 + c];
#pragma unroll
            for (int i = 0; i < 16; ++i) acc[i] += xt[(g * 16 + i) * 64 + k] * w;
        }
        __bf16* o = (m == 0) ? vv : kk;
#pragma unroll
        for (int i = 0; i < 16; ++i) {
            int gr = row0 + g * 16 + i;
            if (gr < N) o[(size_t)gr * CH + c] = (__bf16)acc[i];
        }
    }
    __syncthreads();
    for (int i = t; i < 64 * 64; i += 256) Wl[0][i] = Wq[i];
    __syncthreads();
    {
        float acc[16];
#pragma unroll
        for (int i = 0; i < 16; ++i) acc[i] = 0.0f;
        for (int k = 0; k < 64; ++k) {
            float w = Wl[0][k * 64 + c];
#pragma unroll
            for (int i = 0; i < 16; ++i) acc[i] += xt[(g * 16 + i) * 64 + k] * w;
        }
#pragma unroll
        for (int i = 0; i < 16; ++i) {
            int gr = row0 + g * 16 + i;
            if (gr < N) qq[(size_t)gr * CH + c] = (__bf16)acc[i];
        }
    }
}

// ---------------------------------------------------------------------------
// Counting sort by dst: hist -> 2-level exclusive scan -> scatter
// ---------------------------------------------------------------------------
__global__ void k_hist(const int* __restrict__ dstA, int* __restrict__ cnt, int E, int Etot)
{
    int e = blockIdx.x * blockDim.x + threadIdx.x;
    if (e < Etot) {
        int d = (e < E) ? dstA[e] : (e - E);
        atomicAdd(&cnt[d], 1);
    }
}

__global__ __launch_bounds__(256) void k_scan_a(
    const int* __restrict__ cnt, int* __restrict__ exc, int* __restrict__ bsum, int N)
{
    __shared__ int sh[256];
    const int b = blockIdx.x, t = threadIdx.x;
    const int base = b * 1024 + t * 4;
    int v0 = (base + 0 < N) ? cnt[base + 0] : 0;
    int v1 = (base + 1 < N) ? cnt[base + 1] : 0;
    int v2 = (base + 2 < N) ? cnt[base + 2] : 0;
    int v3 = (base + 3 < N) ? cnt[base + 3] : 0;
    int s = v0 + v1 + v2 + v3;
    sh[t] = s;
    __syncthreads();
    for (int off = 1; off < 256; off <<= 1) {
        int x = (t >= off) ? sh[t - off] : 0;
        __syncthreads();
        sh[t] += x;
        __syncthreads();
    }
    int p = sh[t] - s;  // exclusive prefix of this thread's chunk
    if (t == 255) bsum[b] = sh[255];
    if (base + 0 < N) exc[base + 0] = p; p += v0;
    if (base + 1 < N) exc[base + 1] = p; p += v1;
    if (base + 2 < N) exc[base + 2] = p; p += v2;
    if (base + 3 < N) exc[base + 3] = p;
}

__global__ __launch_bounds__(256) void k_scan_b(int* __restrict__ bsum, int nb)
{
    __shared__ int sh[256];
    const int t = threadIdx.x;
    int v = (t < nb) ? bsum[t] : 0;
    sh[t] = v;
    __syncthreads();
    for (int off = 1; off < 256; off <<= 1) {
        int x = (t >= off) ? sh[t - off] : 0;
        __syncthreads();
        sh[t] += x;
        __syncthreads();
    }
    if (t < nb) bsum[t] = sh[t] - v;  // exclusive
}

__global__ void k_scan_c(const int* __restrict__ exc, const int* __restrict__ bsum,
                         int* __restrict__ cur, int N)
{
    int i = blockIdx.x * blockDim.x + threadIdx.x;
    if (i < N) cur[i] = exc[i] + bsum[i >> 10];
}

__global__ void k_scatter(const int* __restrict__ srcA, const int* __restrict__ dstA,
                          int* __restrict__ cur, int* __restrict__ sortedS,
                          int* __restrict__ sortedD, int E, int Etot)
{
    int e = blockIdx.x * blockDim.x + threadIdx.x;
    if (e < Etot) {
        int d, s;
        if (e < E) { d = dstA[e]; s = srcA[e]; }
        else       { d = s = e - E; }
        int p = atomicAdd(&cur[d], 1);
        sortedS[p] = s;
        sortedD[p] = d;
    }
}

// ---------------------------------------------------------------------------
// MFMA edge kernel on dst-sorted edges, software-pipelined.
//  - 16 edges per wave-iteration, 16x16x32 bf16 MFMA
//  - consecutive edges share dst -> run-combine equal-dst contributions in
//    registers before the atomic flush (~3.4x fewer atomics), and dst-side
//    gathers (pos, q) become broadcasts
// ---------------------------------------------------------------------------
__global__ __launch_bounds__(256) void k_edge_mfma(
    const int* __restrict__ sortedS, const int* __restrict__ sortedD,
    const float* __restrict__ pos,
    const __bf16* __restrict__ vvb, const __bf16* __restrict__ kkb, const __bf16* __restrict__ qqb,
    const float* __restrict__ P1, const float* __restrict__ pb1,
    const float* __restrict__ P2, const float* __restrict__ pb2,
    const float* __restrict__ A1, const float* __restrict__ ab1,
    const float* __restrict__ A2, const float* __restrict__ ab2,
    float* __restrict__ num, float* __restrict__ den,
    int Etot, int nChunks)
{
    __shared__ __align__(16) __bf16 Wtab[3][8][64][8];   // 24.0 KiB
    __shared__ __align__(16) __bf16 tb[4][16][72];       //  9.0 KiB

    const int t = threadIdx.x;
    for (int i = t; i < 3 * 4096; i += 256) {
        int mat = i >> 12, r = i & 4095;
        int j = r & 7, lane = (r >> 3) & 63, ksnt = r >> 9;
        int ks = ksnt & 1, nt = ksnt >> 1;
        int k = ks * 32 + ((lane >> 4) & 3) * 8 + j;
        int n = nt * 16 + (lane & 15);
        const float* W = (mat == 0) ? P2 : ((mat == 1) ? A1 : A2);
        Wtab[mat][ksnt][lane][j] = (__bf16)W[k * 64 + n];
    }
    __syncthreads();

    const int l = t & 63, wid = t >> 6, lg = l >> 4, lm = l & 15;
    __bf16* tbw = &tb[wid][0][0];

    float pb1r[4], pb2r[4], ab1r[4], ab2r[4];
    bf16x8 p1f[4];
#pragma unroll
    for (int nt = 0; nt < 4; ++nt) {
        int co = nt * 16 + lm;
        pb1r[nt] = pb1[co]; pb2r[nt] = pb2[co];
        ab1r[nt] = ab1[co]; ab2r[nt] = ab2[co];
        bf16x8 f;
#pragma unroll
        for (int j = 0; j < 8; ++j)
            f[j] = (__bf16)((lg == 0 && j < 3) ? P1[j * 64 + co] : 0.0f);
        p1f[nt] = f;
    }

    int ch = blockIdx.x;
    if (ch >= nChunks) return;

    // ---- pipeline prologue: indices + gathers for first chunk
    int sC = 0, dC = 0;
    {
        int eA = ch * 64 + wid * 16 + lm;
        if (eA < Etot) { sC = sortedS[eA]; dC = sortedD[eA]; }
    }
    float pdl[3];
    bf16x8 qmk0, qmk1;
    {
        const float* ps = pos + (size_t)sC * 3;
        const float* pd = pos + (size_t)dC * 3;
        pdl[0] = pd[0] - ps[0]; pdl[1] = pd[1] - ps[1]; pdl[2] = pd[2] - ps[2];
        const __bf16* qp = qqb + (size_t)dC * 64 + lg * 8;
        const __bf16* kp = kkb + (size_t)sC * 64 + lg * 8;
        bf16x8 q0 = *(const bf16x8*)qp, q1 = *(const bf16x8*)(qp + 32);
        bf16x8 k0 = *(const bf16x8*)kp, k1 = *(const bf16x8*)(kp + 32);
#pragma unroll
        for (int j = 0; j < 8; ++j) {
            qmk0[j] = (__bf16)((float)q0[j] - (float)k0[j]);
            qmk1[j] = (__bf16)((float)q1[j] - (float)k1[j]);
        }
    }

    for (;;) {
        const int e0 = ch * 64 + wid * 16;
        const int chn = ch + gridDim.x;
        const bool hn = chn < nChunks;

        // ---- stage A: next chunk indices (issued early)
        int sN = 0, dN = 0;
        if (hn) {
            int eA = chn * 64 + wid * 16 + lm;
            if (eA < Etot) { sN = sortedS[eA]; dN = sortedD[eA]; }
        }

        // ---- stage B: v gathers for current (consumed at scatter, end of body)
        int dD[4];
        __bf16 vpre[4][4];
#pragma unroll
        for (int jj = 0; jj < 4; ++jj) {
            int sD = __shfl(sC, lg * 4 + jj);
            dD[jj] = __shfl(dC, lg * 4 + jj);
            const __bf16* vp = vvb + (size_t)sD * 64 + lm;
#pragma unroll
            for (int nt = 0; nt < 4; ++nt) vpre[jj][nt] = vp[nt * 16];
        }

        // ---- P1 (K=3, zero-padded; only lane-group 0 carries data)
        bf16x8 af;
        af[0] = (lg == 0) ? (__bf16)pdl[0] : (__bf16)0.0f;
        af[1] = (lg == 0) ? (__bf16)pdl[1] : (__bf16)0.0f;
        af[2] = (lg == 0) ? (__bf16)pdl[2] : (__bf16)0.0f;
        af[3] = af[4] = af[5] = af[6] = af[7] = (__bf16)0.0f;
        f32x4 acc[4];
#pragma unroll
        for (int nt = 0; nt < 4; ++nt) {
            f32x4 a; a[0] = a[1] = a[2] = a[3] = pb1r[nt];
            acc[nt] = __builtin_amdgcn_mfma_f32_16x16x32_bf16(af, p1f[nt], a, 0, 0, 0);
        }
#pragma unroll
        for (int nt = 0; nt < 4; ++nt)
#pragma unroll
            for (int jj = 0; jj < 4; ++jj)
                tbw[(lg * 4 + jj) * 72 + nt * 16 + lm] = (__bf16)silu_f(acc[nt][jj]);
        bf16x8 aX0 = *(const bf16x8*)&tbw[lm * 72 + lg * 8];
        bf16x8 aX1 = *(const bf16x8*)&tbw[lm * 72 + 32 + lg * 8];

        // ---- P2
#pragma unroll
        for (int nt = 0; nt < 4; ++nt) {
            f32x4 a; a[0] = a[1] = a[2] = a[3] = pb2r[nt];
            a = __builtin_amdgcn_mfma_f32_16x16x32_bf16(aX0, *(const bf16x8*)&Wtab[0][nt * 2 + 0][l][0], a, 0, 0, 0);
            a = __builtin_amdgcn_mfma_f32_16x16x32_bf16(aX1, *(const bf16x8*)&Wtab[0][nt * 2 + 1][l][0], a, 0, 0, 0);
            acc[nt] = a;
        }
        float dlt[4][4];
#pragma unroll
        for (int nt = 0; nt < 4; ++nt)
#pragma unroll
            for (int jj = 0; jj < 4; ++jj) {
                float dv = silu_f(acc[nt][jj]);
                dlt[nt][jj] = dv;
                tbw[(lg * 4 + jj) * 72 + nt * 16 + lm] = (__bf16)dv;
            }

        // ---- stage C: next-chunk gathers (pos-delta + q-k), hide under A1/A2
        float pdlN[3];
        bf16x8 qmkN0, qmkN1;
        if (hn) {
            const float* ps = pos + (size_t)sN * 3;
            const float* pd = pos + (size_t)dN * 3;
            pdlN[0] = pd[0] - ps[0]; pdlN[1] = pd[1] - ps[1]; pdlN[2] = pd[2] - ps[2];
            const __bf16* qp = qqb + (size_t)dN * 64 + lg * 8;
            const __bf16* kp = kkb + (size_t)sN * 64 + lg * 8;
            bf16x8 q0 = *(const bf16x8*)qp, q1 = *(const bf16x8*)(qp + 32);
            bf16x8 k0 = *(const bf16x8*)kp, k1 = *(const bf16x8*)(kp + 32);
#pragma unroll
            for (int j = 0; j < 8; ++j) {
                qmkN0[j] = (__bf16)((float)q0[j] - (float)k0[j]);
                qmkN1[j] = (__bf16)((float)q1[j] - (float)k1[j]);
            }
        }

        // alpha0 = (q-k) + delta  (delta re-read in A-layout)
        bf16x8 dA0 = *(const bf16x8*)&tbw[lm * 72 + lg * 8];
        bf16x8 dA1 = *(const bf16x8*)&tbw[lm * 72 + 32 + lg * 8];
        bf16x8 aA0, aA1;
#pragma unroll
        for (int j = 0; j < 8; ++j) {
            aA0[j] = (__bf16)((float)qmk0[j] + (float)dA0[j]);
            aA1[j] = (__bf16)((float)qmk1[j] + (float)dA1[j]);
        }

        // ---- A1
#pragma unroll
        for (int nt = 0; nt < 4; ++nt) {
            f32x4 a; a[0] = a[1] = a[2] = a[3] = ab1r[nt];
            a = __builtin_amdgcn_mfma_f32_16x16x32_bf16(aA0, *(const bf16x8*)&Wtab[1][nt * 2 + 0][l][0], a, 0, 0, 0);
            a = __builtin_amdgcn_mfma_f32_16x16x32_bf16(aA1, *(const bf16x8*)&Wtab[1][nt * 2 + 1][l][0], a, 0, 0, 0);
            acc[nt] = a;
        }
#pragma unroll
        for (int nt = 0; nt < 4; ++nt)
#pragma unroll
            for (int jj = 0; jj < 4; ++jj)
                tbw[(lg * 4 + jj) * 72 + nt * 16 + lm] = (__bf16)silu_f(acc[nt][jj]);
        bf16x8 aY0 = *(const bf16x8*)&tbw[lm * 72 + lg * 8];
        bf16x8 aY1 = *(const bf16x8*)&tbw[lm * 72 + 32 + lg * 8];

        // ---- A2
#pragma unroll
        for (int nt = 0; nt < 4; ++nt) {
            f32x4 a; a[0] = a[1] = a[2] = a[3] = ab2r[nt];
            a = __builtin_amdgcn_mfma_f32_16x16x32_bf16(aY0, *(const bf16x8*)&Wtab[2][nt * 2 + 0][l][0], a, 0, 0, 0);
            a = __builtin_amdgcn_mfma_f32_16x16x32_bf16(aY1, *(const bf16x8*)&Wtab[2][nt * 2 + 1][l][0], a, 0, 0, 0);
            acc[nt] = a;
        }

        // ---- scatter with equal-dst run-combine over the 4 consecutive edges
        {
            float ad[4] = {0.f, 0.f, 0.f, 0.f};
            float an[4] = {0.f, 0.f, 0.f, 0.f};
            int curd = dD[0];
#pragma unroll
            for (int jj = 0; jj < 4; ++jj) {
                const int eD = e0 + lg * 4 + jj;
                const bool v = eD < Etot;
                if (dD[jj] != curd) {
                    const size_t ob = (size_t)curd * 64 + lm;
#pragma unroll
                    for (int nt = 0; nt < 4; ++nt) {
                        atomicAdd(&den[ob + nt * 16], ad[nt]);
                        atomicAdd(&num[ob + nt * 16], an[nt]);
                        ad[nt] = 0.f; an[nt] = 0.f;
                    }
                    curd = dD[jj];
                }
#pragma unroll
                for (int nt = 0; nt < 4; ++nt) {
                    float ex = v ? __expf(silu_f(acc[nt][jj])) : 0.0f;
                    ad[nt] += ex;
                    an[nt] += ex * ((float)vpre[jj][nt] + dlt[nt][jj]);
                }
            }
            const size_t ob = (size_t)curd * 64 + lm;
#pragma unroll
            for (int nt = 0; nt < 4; ++nt) {
                atomicAdd(&den[ob + nt * 16], ad[nt]);
                atomicAdd(&num[ob + nt * 16], an[nt]);
            }
        }

        if (!hn) break;
        sC = sN; dC = dN;
        pdl[0] = pdlN[0]; pdl[1] = pdlN[1]; pdl[2] = pdlN[2];
        qmk0 = qmkN0; qmk1 = qmkN1;
        ch = chn;
    }
}

// ---------------------------------------------------------------------------
// Kernel: pre = num/den; o = pre @ Wout + bout ; accumulate BN2 stats
// ---------------------------------------------------------------------------
__global__ __launch_bounds__(256) void k_out(
    const float* __restrict__ num, const float* __restrict__ den,
    const float* __restrict__ Wout, const float* __restrict__ bout,
    float* __restrict__ o, float* __restrict__ ssum, float* __restrict__ ssq, int N)
{
    __shared__ float xt[64 * 64];
    __shared__ float Wl[64 * 64];
    __shared__ float red[2][4][64];
    const int t = threadIdx.x, c = t & 63, g = t >> 6;
    const int row0 = blockIdx.x * 64;

    for (int i = t; i < 64 * 64; i += 256) {
        int r = i >> 6, cc = i & 63;
        int gr = row0 + r;
        xt[i] = (gr < N) ? num[(size_t)gr * CH + cc] / den[(size_t)gr * CH + cc] : 0.0f;
        Wl[i] = Wout[i];
    }
    __syncthreads();

    float acc[16];
    const float b = bout[c];
#pragma unroll
    for (int i = 0; i < 16; ++i) acc[i] = b;
    for (int k = 0; k < 64; ++k) {
        float w = Wl[k * 64 + c];
#pragma unroll
        for (int i = 0; i < 16; ++i) acc[i] += xt[(g * 16 + i) * 64 + k] * w;
    }
    float s = 0.0f, ss = 0.0f;
#pragma unroll
    for (int i = 0; i < 16; ++i) {
        int gr = row0 + g * 16 + i;
        if (gr < N) {
            o[(size_t)gr * CH + c] = acc[i];
            s += acc[i];
            ss += acc[i] * acc[i];
        }
    }
    red[0][g][c] = s;
    red[1][g][c] = ss;
    __syncthreads();
    if (g == 0) {
        atomicAdd(&ssum[c], red[0][0][c] + red[0][1][c] + red[0][2][c] + red[0][3][c]);
        atomicAdd(&ssq[c],  red[1][0][c] + red[1][1][c] + red[1][2][c] + red[1][3][c]);
    }
}

// ---------------------------------------------------------------------------
__global__ void k_final(const float* __restrict__ o, const float* __restrict__ scale,
                        const float* __restrict__ shift, float* __restrict__ out, int total)
{
    int i = blockIdx.x * blockDim.x + threadIdx.x;
    if (i < total) {
        int c = i & 63;
        out[i] = o[i] * scale[c] + shift[c];
    }
}

// ---------------------------------------------------------------------------
extern "C" void kernel_launch(void* const* d_in, const int* in_sizes, int n_in,
                              void* d_out, int out_size, void* d_ws, size_t ws_size,
                              hipStream_t stream)
{
    const float* x      = (const float*)d_in[0];
    const float* pos    = (const float*)d_in[1];
    const int*   ei     = (const int*)d_in[2];
    const float* Win    = (const float*)d_in[3];
    const float* bin    = (const float*)d_in[4];
    const float* gin    = (const float*)d_in[5];
    const float* betain = (const float*)d_in[6];
    const float* Wv     = (const float*)d_in[7];
    const float* Wk     = (const float*)d_in[8];
    const float* Wq     = (const float*)d_in[9];
    const float* P1     = (const float*)d_in[10];
    const float* pb1    = (const float*)d_in[11];
    const float* P2     = (const float*)d_in[12];
    const float* pb2    = (const float*)d_in[13];
    const float* A1     = (const float*)d_in[14];
    const float* ab1    = (const float*)d_in[15];
    const float* A2     = (const float*)d_in[16];
    const float* ab2    = (const float*)d_in[17];
    const float* Wout   = (const float*)d_in[18];
    const float* bout   = (const float*)d_in[19];
    const float* gout   = (const float*)d_in[20];
    const float* betaout= (const float*)d_in[21];

    const int N = in_sizes[0] / CH;
    const int E = in_sizes[2] / 2;
    const int Etot = E + N;
    const int* srcA = ei;
    const int* dstA = ei + E;

    float* ws = (float*)d_ws;
    const size_t NC = (size_t)N * CH;
    float* h    = ws;                    // N*C f32 (reused as o after edge pass)
    float* num  = h + NC;                // N*C f32
    float* den  = num + NC;              // N*C f32
    float* st   = den + NC;              // 512 f32 stats
    int* cnt    = (int*)(st + 512);      // N   (zeroed with num/den/st)
    int* exc    = cnt + N;               // N
    int* cur    = exc + N;               // N
    int* bsum   = cur + N;               // 256
    int* sortedS= bsum + 256;            // Etot
    int* sortedD= sortedS + Etot;        // Etot
    __bf16* vvb = (__bf16*)(sortedD + Etot);  // N*C bf16
    __bf16* kkb = vvb + NC;                   // N*C bf16
    __bf16* qqb = kkb + NC;                   // N*C bf16

    // zero num, den, stats, cnt in one shot (contiguous)
    hipMemsetAsync(num, 0, (2 * NC + 512 + (size_t)N) * sizeof(float), stream);

    // ---- counting sort by dst
    const int nbScan = (N + 1023) / 1024;
    k_hist<<<(Etot + 255) / 256, 256, 0, stream>>>(dstA, cnt, E, Etot);
    k_scan_a<<<nbScan, 256, 0, stream>>>(cnt, exc, bsum, N);
    k_scan_b<<<1, 256, 0, stream>>>(bsum, nbScan);
    k_scan_c<<<(N + 255) / 256, 256, 0, stream>>>(exc, bsum, cur, N);
    k_scatter<<<(Etot + 255) / 256, 256, 0, stream>>>(srcA, dstA, cur, sortedS, sortedD, E, Etot);

    // ---- node pipeline
    const int nb = (N + 63) / 64;
    k_lin_in<<<nb, 256, 0, stream>>>(x, Win, bin, h, st, st + 64, N);
    k_stats<<<1, 64, 0, stream>>>(st, st + 64, gin, betain, st + 128, st + 192, N);
    k_vkq<<<nb, 256, 0, stream>>>(h, st + 128, st + 192, Wv, Wk, Wq, vvb, kkb, qqb, N);

    // ---- fused edge pass on sorted edges
    const int nChunks = (Etot + 63) / 64;
    const int grid = (nChunks < 2048) ? nChunks : 2048;
    k_edge_mfma<<<grid, 256, 0, stream>>>(sortedS, sortedD, pos, vvb, kkb, qqb,
                                          P1, pb1, P2, pb2, A1, ab1, A2, ab2,
                                          num, den, Etot, nChunks);

    k_out<<<nb, 256, 0, stream>>>(num, den, Wout, bout, h, st + 256, st + 320, N);
    k_stats<<<1, 64, 0, stream>>>(st + 256, st + 320, gout, betaout, st + 384, st + 448, N);
    k_final<<<(int)((NC + 255) / 256), 256, 0, stream>>>(h, st + 384, st + 448,
                                                         (float*)d_out, (int)NC);
}